// Round 6
// baseline (529.320 us; speedup 1.0000x reference)
//
#include <hip/hip_runtime.h>
#include <cstdint>
#include <cstddef>

// GLA layer: B=4, T=4096, D=1024, H=16, S=64
// Real pipeline identical to round 5 (169 us gemm1, MfmaUtil 26).
// THIS ROUND: + two ablation probes appended after all real work,
// writing only to dead scratch (Ac). P2 = K-loop without staging/vmcnt
// (LDS pre-filled; ds_read+lgkm+MFMA+barrier only). P3 = MFMA+barrier
// only (frags loaded once). 4 reps x 32 phases each, grid 256.
// Probe durs/counters split the hypothesis space: staging-DMA vs
// LDS-read serialization vs MFMA/barrier geometry.

typedef _Float16 f16;
typedef _Float16 f16x2 __attribute__((ext_vector_type(2)));
typedef _Float16 f16x8 __attribute__((ext_vector_type(8)));
typedef float    f32x4 __attribute__((ext_vector_type(4)));

__device__ __forceinline__ void gload_lds16(const void* g, void* l) {
  __builtin_amdgcn_global_load_lds(
      (const __attribute__((address_space(1))) void*)g,
      (__attribute__((address_space(3))) void*)l, 16, 0, 0);
}

__device__ __forceinline__ float sigmoidf_(float x) {
  return 1.0f / (1.0f + __expf(-x));
}

// ---------------- fused cast+pack fp32 -> fp16 ----------------
__global__ __launch_bounds__(256) void cast_pack(
    const float* __restrict__ x, const float* __restrict__ gw,
    const float* __restrict__ vw, const float* __restrict__ ow,
    f16* __restrict__ xh, f16* __restrict__ wgv, f16* __restrict__ owb) {
  const int XG = 2097152, GG = 262144, VG = 131072, OG = 131072;
  int id = blockIdx.x * 256 + threadIdx.x;
  const float* src;
  f16* dst;
  if (id < XG) {
    src = x + (size_t)id * 8;
    dst = xh + (size_t)id * 8;
  } else if (id < XG + GG) {
    int g = id - XG;
    int row = g >> 7, col = g & 127;
    int drow = (row < 1024) ? row : (1024 + 2 * (row - 1024));
    src = gw + ((size_t)row << 10) + col * 8;
    dst = wgv + ((size_t)drow << 10) + col * 8;
  } else if (id < XG + GG + VG) {
    int g = id - XG - GG;
    int row = g >> 7, col = g & 127;
    int drow = 1024 + 2 * row + 1;
    src = vw + ((size_t)row << 10) + col * 8;
    dst = wgv + ((size_t)drow << 10) + col * 8;
  } else if (id < XG + GG + VG + OG) {
    int g = id - XG - GG - VG;
    src = ow + (size_t)g * 8;
    dst = owb + (size_t)g * 8;
  } else {
    return;
  }
  float4 v0 = ((const float4*)src)[0], v1 = ((const float4*)src)[1];
  f16x8 o;
  o[0] = (f16)v0.x; o[1] = (f16)v0.y; o[2] = (f16)v0.z; o[3] = (f16)v0.w;
  o[4] = (f16)v1.x; o[5] = (f16)v1.y; o[6] = (f16)v1.z; o[7] = (f16)v1.w;
  *(f16x8*)dst = o;
}

// opaque LDS read: invisible to the compiler's waitcnt alias tracking.
#define DSREAD(dst, addr, off)                                        \
  asm volatile("ds_read_b128 %0, %1 offset:%2"                       \
               : "=v"(dst)                                            \
               : "v"(addr), "i"(off))

#define WAIT_LGKM(n)                                                  \
  asm volatile("s_waitcnt lgkmcnt(" #n ")" ::: "memory");             \
  __builtin_amdgcn_sched_barrier(0)

// opaque barrier (no compiler-attached waits)
#define SBAR asm volatile("s_barrier" ::: "memory")

// ---- 256x256 fp16 MFMA GEMM: C[N,M] = A[N,K] * B[M,K]^T ----
template <int EPI>
__global__ __launch_bounds__(512, 2) void gemm256(
    const f16* __restrict__ A, const f16* __restrict__ Bw,
    const float* __restrict__ gate_b, void* __restrict__ o0v,
    void* __restrict__ o1v, int Mtiles) {
  constexpr int K = 1024;
  __shared__ __align__(16) f16 SH[65536];  // 128 KiB
  f16* LA = SH;          // 4 regions x 8192 f16 (16 KB each)
  f16* LB = SH + 32768;

  const int tid  = threadIdx.x;
  const int lane = tid & 63;
  const int l15  = lane & 15;
  const int oct4 = lane >> 4;
  const int wid  = tid >> 6;
  const int wr   = wid >> 2;
  const int wc   = wid & 3;

  const int nwg = gridDim.x;
  const int bid = blockIdx.x;
  const int swz = (bid & 7) * (nwg >> 3) + (bid >> 3);
  const int m0 = (swz % Mtiles) * 256;
  const int n0 = (swz / Mtiles) * 256;

  const int srow = tid >> 2;
  const int soct = (tid & 3) ^ ((srow >> 1) & 3);
  const f16* Ag = A  + (size_t)(n0 + srow) * K + soct * 8;
  const f16* Bg = Bw + (size_t)(m0 + srow) * K + soct * 8;
  f16* Al = LA + tid * 8;
  f16* Bl = LB + tid * 8;

  const int fswz  = oct4 ^ ((l15 >> 1) & 3);
  const unsigned shbase = (unsigned)(uintptr_t)(&SH[0]);
  const int aaddr = (int)shbase + ((wr * 128 + l15) * 4 + fswz) * 16;
  const int baddr = (int)shbase + 65536 + ((wc * 64 + l15) * 4 + fswz) * 16;

  f32x4 acc[8][4];
#pragma unroll
  for (int mm = 0; mm < 8; ++mm)
#pragma unroll
    for (int nn = 0; nn < 4; ++nn)
#pragma unroll
      for (int e = 0; e < 4; ++e) acc[mm][nn][e] = 0.f;

#define STAGE_AB(kt)                                                  \
  do {                                                                \
    const f16* sa_ = Ag + (kt) * 32;                                  \
    const f16* sb_ = Bg + (kt) * 32;                                  \
    f16* da_ = Al + ((kt) & 3) * 8192;                                \
    f16* db_ = Bl + ((kt) & 3) * 8192;                                \
    gload_lds16(sa_, da_);                                            \
    gload_lds16(sa_ + 128 * K, da_ + 4096);                           \
    gload_lds16(sb_, db_);                                            \
    gload_lds16(sb_ + 128 * K, db_ + 4096);                           \
  } while (0)

  STAGE_AB(0);
  STAGE_AB(1);
  STAGE_AB(2);
  asm volatile("s_waitcnt vmcnt(8)" ::: "memory");
  SBAR;
  __builtin_amdgcn_sched_barrier(0);

  f16x8 af[8], bf[4];
  DSREAD(bf[0], baddr, 0);    DSREAD(bf[1], baddr, 1024);
  DSREAD(bf[2], baddr, 2048); DSREAD(bf[3], baddr, 3072);
  DSREAD(af[0], aaddr, 0);    DSREAD(af[1], aaddr, 1024);
  DSREAD(af[2], aaddr, 2048); DSREAD(af[3], aaddr, 3072);
  DSREAD(af[4], aaddr, 4096); DSREAD(af[5], aaddr, 5120);
  DSREAD(af[6], aaddr, 6144); DSREAD(af[7], aaddr, 7168);

#pragma unroll
  for (int kt = 0; kt < 32; ++kt) {
    if (kt <= 28) STAGE_AB(kt + 3);

    __builtin_amdgcn_s_setprio(1);
    WAIT_LGKM(7);
#pragma unroll
    for (int nn = 0; nn < 4; ++nn)
      acc[0][nn] = __builtin_amdgcn_mfma_f32_16x16x32_f16(
          af[0], bf[nn], acc[0][nn], 0, 0, 0);
    WAIT_LGKM(4);
#pragma unroll
    for (int mm = 1; mm < 4; ++mm)
#pragma unroll
      for (int nn = 0; nn < 4; ++nn)
        acc[mm][nn] = __builtin_amdgcn_mfma_f32_16x16x32_f16(
            af[mm], bf[nn], acc[mm][nn], 0, 0, 0);
    WAIT_LGKM(0);
#pragma unroll
    for (int mm = 4; mm < 8; ++mm)
#pragma unroll
      for (int nn = 0; nn < 4; ++nn)
        acc[mm][nn] = __builtin_amdgcn_mfma_f32_16x16x32_f16(
            af[mm], bf[nn], acc[mm][nn], 0, 0, 0);
    __builtin_amdgcn_s_setprio(0);
    __builtin_amdgcn_sched_barrier(0);

    if (kt < 31) {
      if (kt <= 28) {
        asm volatile("s_waitcnt vmcnt(8)" ::: "memory");
      } else if (kt == 29) {
        asm volatile("s_waitcnt vmcnt(4)" ::: "memory");
      } else {
        asm volatile("s_waitcnt vmcnt(0)" ::: "memory");
      }
      SBAR;
      __builtin_amdgcn_sched_barrier(0);
      const int ro = ((kt + 1) & 3) * 16384;
      const int aP = aaddr + ro;
      const int bP = baddr + ro;
      DSREAD(bf[0], bP, 0);    DSREAD(bf[1], bP, 1024);
      DSREAD(bf[2], bP, 2048); DSREAD(bf[3], bP, 3072);
      DSREAD(af[0], aP, 0);    DSREAD(af[1], aP, 1024);
      DSREAD(af[2], aP, 2048); DSREAD(af[3], aP, 3072);
      DSREAD(af[4], aP, 4096); DSREAD(af[5], aP, 5120);
      DSREAD(af[6], aP, 6144); DSREAD(af[7], aP, 7168);
    }
  }
#undef STAGE_AB

  // ---------------- epilogues ----------------
  if (EPI == 1) {
    float* out = (float*)o0v;
#pragma unroll
    for (int mm = 0; mm < 8; ++mm)
#pragma unroll
      for (int nn = 0; nn < 4; ++nn) {
        const int m = m0 + wc * 64 + nn * 16 + l15;
#pragma unroll
        for (int r = 0; r < 4; ++r) {
          const int n = n0 + wr * 128 + mm * 16 + oct4 * 4 + r;
          out[(size_t)n * 1024 + m] = acc[mm][nn][r];
        }
      }
    return;
  }

  if (m0 < 1024) {
    float bias[4];
#pragma unroll
    for (int nn = 0; nn < 4; ++nn)
      bias[nn] = gate_b[m0 + wc * 64 + nn * 16 + l15];
    f16* o0 = (f16*)o0v;
#pragma unroll
    for (int ck = 0; ck < 2; ++ck) {
      __builtin_amdgcn_s_barrier();
      asm volatile("" ::: "memory");
      if (wr == ck) {
#pragma unroll
        for (int mm = 0; mm < 8; ++mm)
#pragma unroll
          for (int nn = 0; nn < 4; ++nn) {
            const int ch = wc * 64 + nn * 16 + l15;
#pragma unroll
            for (int r = 0; r < 4; ++r) {
              const int nl = mm * 16 + oct4 * 4 + r;
              SH[nl * 264 + ch] = (f16)sigmoidf_(acc[mm][nn][r] + bias[nn]);
            }
          }
      }
      __builtin_amdgcn_s_barrier();
      asm volatile("" ::: "memory");
#pragma unroll
      for (int j = 0; j < 8; ++j) {
        int s = j * 512 + tid;
        int row = s >> 5, sl = s & 31;
        f16x8 vv = *(const f16x8*)&SH[row * 264 + sl * 8];
        *(f16x8*)(o0 + (size_t)(n0 + ck * 128 + row) * 1024 + m0 + sl * 8) =
            vv;
      }
    }
  } else {
    const int c0 = (m0 - 1024) >> 1;
    float biasv[4];
#pragma unroll
    for (int nn = 0; nn < 4; ++nn) {
      const int ml = wc * 64 + nn * 16 + l15;
      biasv[nn] = gate_b[1024 + c0 + (ml >> 1)];
    }
    f16* o1 = (f16*)o1v;
#pragma unroll
    for (int ck = 0; ck < 2; ++ck) {
      __builtin_amdgcn_s_barrier();
      asm volatile("" ::: "memory");
      if (wr == ck) {
#pragma unroll
        for (int mm = 0; mm < 8; ++mm)
#pragma unroll
          for (int nn = 0; nn < 4; ++nn) {
            const int ml = wc * 64 + nn * 16 + l15;
#pragma unroll
            for (int r = 0; r < 4; ++r) {
              float val = acc[mm][nn][r];
              float pv = __shfl_xor(val, 1, 64);
              if (!(lane & 1)) {
                const int nl = mm * 16 + oct4 * 4 + r;
                SH[nl * 136 + (ml >> 1)] =
                    (f16)(sigmoidf_(val + biasv[nn]) * pv);
              }
            }
          }
      }
      __builtin_amdgcn_s_barrier();
      asm volatile("" ::: "memory");
#pragma unroll
      for (int j = 0; j < 4; ++j) {
        int s = j * 512 + tid;
        int row = s >> 4, sl = s & 15;
        f16x8 vv = *(const f16x8*)&SH[row * 136 + sl * 8];
        *(f16x8*)(o1 + (size_t)(n0 + ck * 128 + row) * 1024 + c0 + sl * 8) =
            vv;
      }
    }
  }
}

// ================== ABLATION PROBES (write only dead scratch) ==========
// MODE 2 = NOSTAGE: LDS pre-filled once; loop = ds_read+lgkm+MFMA+SBAR.
// MODE 3 = PUREMFMA: frags loaded once; loop = MFMA+setprio+SBAR only.
// 4 reps x 32 phases (4x the real K-loop work), grid 256.
template <int MODE>
__global__ __launch_bounds__(512, 2) void gemm_probe(
    const f16* __restrict__ A, const f16* __restrict__ Bw,
    float* __restrict__ guard, int Mtiles) {
  constexpr int K = 1024;
  __shared__ __align__(16) f16 SH[65536];
  f16* LA = SH;
  f16* LB = SH + 32768;

  const int tid  = threadIdx.x;
  const int lane = tid & 63;
  const int l15  = lane & 15;
  const int oct4 = lane >> 4;
  const int wid  = tid >> 6;
  const int wr   = wid >> 2;
  const int wc   = wid & 3;

  const int nwg = gridDim.x;
  const int bid = blockIdx.x;
  const int swz = (bid & 7) * (nwg >> 3) + (bid >> 3);
  const int m0 = (swz % Mtiles) * 256;
  const int n0 = (swz / Mtiles) * 256;

  const int srow = tid >> 2;
  const int soct = (tid & 3) ^ ((srow >> 1) & 3);
  const f16* Ag = A  + (size_t)(n0 + srow) * K + soct * 8;
  const f16* Bg = Bw + (size_t)(m0 + srow) * K + soct * 8;
  f16* Al = LA + tid * 8;
  f16* Bl = LB + tid * 8;

  const int fswz  = oct4 ^ ((l15 >> 1) & 3);
  const unsigned shbase = (unsigned)(uintptr_t)(&SH[0]);
  const int aaddr = (int)shbase + ((wr * 128 + l15) * 4 + fswz) * 16;
  const int baddr = (int)shbase + 65536 + ((wc * 64 + l15) * 4 + fswz) * 16;

  f32x4 acc[8][4];
#pragma unroll
  for (int mm = 0; mm < 8; ++mm)
#pragma unroll
    for (int nn = 0; nn < 4; ++nn)
#pragma unroll
      for (int e = 0; e < 4; ++e) acc[mm][nn][e] = 0.f;

  // prologue: fill all 4 LDS regions once, full drain
#pragma unroll
  for (int kt = 0; kt < 4; ++kt) {
    const f16* sa_ = Ag + kt * 32;
    const f16* sb_ = Bg + kt * 32;
    f16* da_ = Al + kt * 8192;
    f16* db_ = Bl + kt * 8192;
    gload_lds16(sa_, da_);
    gload_lds16(sa_ + 128 * K, da_ + 4096);
    gload_lds16(sb_, db_);
    gload_lds16(sb_ + 128 * K, db_ + 4096);
  }
  asm volatile("s_waitcnt vmcnt(0)" ::: "memory");
  SBAR;
  __builtin_amdgcn_sched_barrier(0);

  f16x8 af[8], bf[4];
  if (MODE == 3) {
    DSREAD(bf[0], baddr, 0);    DSREAD(bf[1], baddr, 1024);
    DSREAD(bf[2], baddr, 2048); DSREAD(bf[3], baddr, 3072);
    DSREAD(af[0], aaddr, 0);    DSREAD(af[1], aaddr, 1024);
    DSREAD(af[2], aaddr, 2048); DSREAD(af[3], aaddr, 3072);
    DSREAD(af[4], aaddr, 4096); DSREAD(af[5], aaddr, 5120);
    DSREAD(af[6], aaddr, 6144); DSREAD(af[7], aaddr, 7168);
    WAIT_LGKM(0);
  }

#pragma unroll 1
  for (int rep = 0; rep < 4; ++rep) {
#pragma unroll 1
    for (int k8 = 0; k8 < 8; ++k8) {
#pragma unroll
      for (int r = 0; r < 4; ++r) {
        if (MODE == 2) {
          const int aP = aaddr + r * 16384;
          const int bP = baddr + r * 16384;
          DSREAD(bf[0], bP, 0);    DSREAD(bf[1], bP, 1024);
          DSREAD(bf[2], bP, 2048); DSREAD(bf[3], bP, 3072);
          DSREAD(af[0], aP, 0);    DSREAD(af[1], aP, 1024);
          DSREAD(af[2], aP, 2048); DSREAD(af[3], aP, 3072);
          DSREAD(af[4], aP, 4096); DSREAD(af[5], aP, 5120);
          DSREAD(af[6], aP, 6144); DSREAD(af[7], aP, 7168);
        }
        __builtin_amdgcn_s_setprio(1);
        if (MODE == 2) { WAIT_LGKM(7); }
#pragma unroll
        for (int nn = 0; nn < 4; ++nn)
          acc[0][nn] = __builtin_amdgcn_mfma_f32_16x16x32_f16(
              af[0], bf[nn], acc[0][nn], 0, 0, 0);
        if (MODE == 2) { WAIT_LGKM(4); }
#pragma unroll
        for (int mm = 1; mm < 4; ++mm)
#pragma unroll
          for (int nn = 0; nn < 4; ++nn)
            acc[mm][nn] = __builtin_amdgcn_mfma_f32_16x16x32_f16(
                af[mm], bf[nn], acc[mm][nn], 0, 0, 0);
        if (MODE == 2) { WAIT_LGKM(0); }
#pragma unroll
        for (int mm = 4; mm < 8; ++mm)
#pragma unroll
          for (int nn = 0; nn < 4; ++nn)
            acc[mm][nn] = __builtin_amdgcn_mfma_f32_16x16x32_f16(
                af[mm], bf[nn], acc[mm][nn], 0, 0, 0);
        __builtin_amdgcn_s_setprio(0);
        __builtin_amdgcn_sched_barrier(0);
        SBAR;
        __builtin_amdgcn_sched_barrier(0);
      }
    }
  }

  // DCE guard: consume every acc element
  float s = 0.f;
#pragma unroll
  for (int mm = 0; mm < 8; ++mm)
#pragma unroll
    for (int nn = 0; nn < 4; ++nn)
#pragma unroll
      for (int e = 0; e < 4; ++e) s += acc[mm][nn][e];
  guard[(size_t)bid * 512 + tid] = s;
}

// ---------------- chunked scan: h_t = a_t*h_{t-1} + bv_t ----------------
__global__ __launch_bounds__(256) void scan_pass1(
    const f16x2* __restrict__ a, const f16x2* __restrict__ bv,
    float2* __restrict__ Ac, float2* __restrict__ Uc) {
  const int c2 = blockIdx.x * 256 + threadIdx.x;
  const int j = blockIdx.y;
  const int b = blockIdx.z;
  const size_t base = ((size_t)(b * 4096 + j * 32)) * 512 + c2;
  float P0 = 1.f, P1 = 1.f, U0 = 0.f, U1 = 0.f;
#pragma unroll 8
  for (int t = 0; t < 32; ++t) {
    const size_t o = base + (size_t)t * 512;
    f16x2 at = a[o], bt = bv[o];
    float a0 = (float)at[0], a1 = (float)at[1];
    P0 *= a0; P1 *= a1;
    U0 = a0 * U0 + (float)bt[0];
    U1 = a1 * U1 + (float)bt[1];
  }
  const size_t o = ((size_t)(b * 128 + j)) * 512 + c2;
  Ac[o] = make_float2(P0, P1);
  Uc[o] = make_float2(U0, U1);
}

__global__ __launch_bounds__(256) void scan_pass2(
    const float* __restrict__ Ac, const float* __restrict__ Uc,
    const float* __restrict__ h_prev, float* __restrict__ Hs,
    float* __restrict__ hlast) {
  __shared__ float SA[4][64], SU[4][64];
  const int tid = threadIdx.x;
  const int seg = tid >> 6;
  const int cl  = tid & 63;
  const int ch  = blockIdx.x * 64 + cl;
  const int b = ch >> 10, c = ch & 1023;
  float A = 1.f, U = 0.f;
  for (int t = 0; t < 32; ++t) {
    const int j = seg * 32 + t;
    const size_t o = ((size_t)(b * 128 + j)) * 1024 + c;
    float av = Ac[o], uv = Uc[o];
    U = av * U + uv;
    A = av * A;
  }
  SA[seg][cl] = A;
  SU[seg][cl] = U;
  __syncthreads();
  float Ae = 1.f, Ue = 0.f;
  for (int s = 0; s < seg; ++s) {
    float av = SA[s][cl], uv = SU[s][cl];
    Ue = av * Ue + uv;
    Ae = av * Ae;
  }
  float H = Ae * h_prev[b * 1024 + c] + Ue;
  for (int t = 0; t < 32; ++t) {
    const int j = seg * 32 + t;
    const size_t o = ((size_t)(b * 128 + j)) * 1024 + c;
    Hs[o] = H;
    H = Ac[o] * H + Uc[o];
  }
  if (seg == 3) hlast[b * 1024 + c] = H;
}

__global__ __launch_bounds__(256) void scan_pass3(
    const f16x2* __restrict__ a, const f16x2* __restrict__ bv,
    const float2* __restrict__ Hs, f16x2* __restrict__ hb) {
  const int c2 = blockIdx.x * 256 + threadIdx.x;
  const int j = blockIdx.y;
  const int b = blockIdx.z;
  const size_t base = ((size_t)(b * 4096 + j * 32)) * 512 + c2;
  float2 H = Hs[((size_t)(b * 128 + j)) * 512 + c2];
  float h0 = H.x, h1 = H.y;
#pragma unroll 8
  for (int t = 0; t < 32; ++t) {
    const size_t o = base + (size_t)t * 512;
    f16x2 at = a[o], bt = bv[o];
    h0 = (float)at[0] * h0 + (float)bt[0];
    h1 = (float)at[1] * h1 + (float)bt[1];
    f16x2 hv; hv[0] = (f16)h0; hv[1] = (f16)h1;
    hb[o] = hv;
  }
}

extern "C" void kernel_launch(void* const* d_in, const int* in_sizes, int n_in,
                              void* d_out, int out_size, void* d_ws,
                              size_t ws_size, hipStream_t stream) {
  const float* x       = (const float*)d_in[0];
  const float* h_prev  = (const float*)d_in[1];
  const float* gate_w  = (const float*)d_in[2];
  const float* gate_b  = (const float*)d_in[3];
  const float* value_w = (const float*)d_in[4];
  const float* out_w   = (const float*)d_in[5];
  float* out = (float*)d_out;

  char* ws = (char*)d_ws;
  f16*   xh   = (f16*)(ws);
  f16*   wgv  = (f16*)(ws + 33554432);
  f16*   owb  = (f16*)(ws + 39845888);
  f16*   abuf = (f16*)(ws + 41943040);
  f16*   bvb  = (f16*)(ws + 75497472);
  float* Ac   = (float*)(ws + 109051904);
  float* Uc   = (float*)(ws + 111149056);
  float* Hs   = (float*)(ws + 113246208);
  float* hlast = out + 16777216;

  cast_pack<<<10240, 256, 0, stream>>>(x, gate_w, value_w, out_w, xh, wgv,
                                       owb);

  gemm256<0><<<dim3(768), 512, 0, stream>>>(xh, wgv, gate_b, abuf, bvb, 12);

  scan_pass1<<<dim3(2, 128, 4), 256, 0, stream>>>(
      (const f16x2*)abuf, (const f16x2*)bvb, (float2*)Ac, (float2*)Uc);
  scan_pass2<<<64, 256, 0, stream>>>(Ac, Uc, h_prev, Hs, hlast);
  scan_pass3<<<dim3(2, 128, 4), 256, 0, stream>>>(
      (const f16x2*)abuf, (const f16x2*)bvb, (const float2*)Hs, (f16x2*)xh);

  gemm256<1><<<dim3(256), 512, 0, stream>>>(xh, owb, nullptr, out, nullptr, 4);

  // ---- ablation probes (after all real work; write only dead Ac) ----
  gemm_probe<2><<<dim3(256), 512, 0, stream>>>(xh, wgv, Ac, 12);
  gemm_probe<3><<<dim3(256), 512, 0, stream>>>(xh, wgv, Ac, 12);
}

// Round 7
// 366.001 us; speedup vs baseline: 1.4462x; 1.4462x over previous
//
#include <hip/hip_runtime.h>
#include <cstdint>
#include <cstddef>

// GLA layer: B=4, T=4096, D=1024, H=16, S=64
// fp16 pipeline, packed weights (a rows | interleaved bg/v rows).
// GEMMs = 256x256 tile, 8 waves, 16x16x32 MFMA, 32 K-phases.
// ROUND 7: staging mechanism swapped from global_load_lds (LDS-DMA engine,
// measured ~9-20 B/cyc/CU shared per-CU ceiling -> the equalizer across
// R0-R5) to REG-STAGING: global_load_dwordx4 -> VGPR -> ds_write_b128.
// Per phase: MFMA cluster (lgkm 7/4/0) -> vmcnt(0) on loads issued a full
// phase earlier -> 4x ds_write (region kt+1) -> lgkm(0) -> issue loads for
// kt+2 -> s_barrier -> 12x ds_read frags(kt+1). One G-set (16 VGPR).
// LDS = 4-region K-step ring x (A,B), 128 KB, XOR-swizzled (swizzled
// global source octet, linear LDS slots). XCD swizzle.
// GEMM1 epilogue: a = sigmoid(.), bv = sigmoid(.)*v (lane-pair shfl),
// LDS-staged f16x8 coalesced stores. Scan: 128 chunks x 32 steps,
// segment-parallel pass2. GEMM2 -> y fp32 direct stores.

typedef _Float16 f16;
typedef _Float16 f16x2 __attribute__((ext_vector_type(2)));
typedef _Float16 f16x8 __attribute__((ext_vector_type(8)));
typedef float    f32x4 __attribute__((ext_vector_type(4)));

__device__ __forceinline__ float sigmoidf_(float x) {
  return 1.0f / (1.0f + __expf(-x));
}

// ---------------- fused cast+pack fp32 -> fp16 ----------------
__global__ __launch_bounds__(256) void cast_pack(
    const float* __restrict__ x, const float* __restrict__ gw,
    const float* __restrict__ vw, const float* __restrict__ ow,
    f16* __restrict__ xh, f16* __restrict__ wgv, f16* __restrict__ owb) {
  const int XG = 2097152, GG = 262144, VG = 131072, OG = 131072;
  int id = blockIdx.x * 256 + threadIdx.x;
  const float* src;
  f16* dst;
  if (id < XG) {
    src = x + (size_t)id * 8;
    dst = xh + (size_t)id * 8;
  } else if (id < XG + GG) {
    int g = id - XG;
    int row = g >> 7, col = g & 127;
    int drow = (row < 1024) ? row : (1024 + 2 * (row - 1024));
    src = gw + ((size_t)row << 10) + col * 8;
    dst = wgv + ((size_t)drow << 10) + col * 8;
  } else if (id < XG + GG + VG) {
    int g = id - XG - GG;
    int row = g >> 7, col = g & 127;
    int drow = 1024 + 2 * row + 1;
    src = vw + ((size_t)row << 10) + col * 8;
    dst = wgv + ((size_t)drow << 10) + col * 8;
  } else if (id < XG + GG + VG + OG) {
    int g = id - XG - GG - VG;
    src = ow + (size_t)g * 8;
    dst = owb + (size_t)g * 8;
  } else {
    return;
  }
  float4 v0 = ((const float4*)src)[0], v1 = ((const float4*)src)[1];
  f16x8 o;
  o[0] = (f16)v0.x; o[1] = (f16)v0.y; o[2] = (f16)v0.z; o[3] = (f16)v0.w;
  o[4] = (f16)v1.x; o[5] = (f16)v1.y; o[6] = (f16)v1.z; o[7] = (f16)v1.w;
  *(f16x8*)dst = o;
}

// opaque LDS read: invisible to the compiler's waitcnt alias tracking.
#define DSREAD(dst, addr, off)                                        \
  asm volatile("ds_read_b128 %0, %1 offset:%2"                       \
               : "=v"(dst)                                            \
               : "v"(addr), "i"(off))

// opaque LDS write (addr VGPR + literal imm offset)
#define DSW(addr, src, off)                                           \
  asm volatile("ds_write_b128 %0, %1 offset:%2"                      \
               :: "v"(addr), "v"(src), "i"(off))

// plain global vector load into VGPRs (normal VMEM path, NOT LDS-DMA)
#define GLOAD(dst, ptr)                                               \
  asm volatile("global_load_dwordx4 %0, %1, off"                     \
               : "=v"(dst)                                            \
               : "v"(ptr))

#define WAIT_LGKM(n)                                                  \
  asm volatile("s_waitcnt lgkmcnt(" #n ")" ::: "memory");             \
  __builtin_amdgcn_sched_barrier(0)

#define WAIT_VM0                                                      \
  asm volatile("s_waitcnt vmcnt(0)" ::: "memory");                    \
  __builtin_amdgcn_sched_barrier(0)

// opaque barrier (no compiler-attached waits)
#define SBAR asm volatile("s_barrier" ::: "memory")

// ---- 256x256 fp16 MFMA GEMM: C[N,M] = A[N,K] * B[M,K]^T ----
// 8 waves (2 token-halves x 4 channel-quarters), per-wave 128x64 output.
template <int EPI>
__global__ __launch_bounds__(512, 2) void gemm256(
    const f16* __restrict__ A, const f16* __restrict__ Bw,
    const float* __restrict__ gate_b, void* __restrict__ o0v,
    void* __restrict__ o1v, int Mtiles) {
  constexpr int K = 1024;
  __shared__ __align__(16) f16 SH[65536];  // 128 KiB

  const int tid  = threadIdx.x;
  const int lane = tid & 63;
  const int l15  = lane & 15;
  const int oct4 = lane >> 4;
  const int wid  = tid >> 6;
  const int wr   = wid >> 2;
  const int wc   = wid & 3;

  // bijective XCD swizzle (grid % 8 == 0 for both launches)
  const int nwg = gridDim.x;
  const int bid = blockIdx.x;
  const int swz = (bid & 7) * (nwg >> 3) + (bid >> 3);
  const int m0 = (swz % Mtiles) * 256;
  const int n0 = (swz / Mtiles) * 256;

  // staging: thread covers (row=tid>>2, physOct=(tid&3)^((row>>1)&3))
  const int srow = tid >> 2;
  const int soct = (tid & 3) ^ ((srow >> 1) & 3);
  const f16* AgL = A  + (size_t)(n0 + srow) * K + soct * 8;
  const f16* AgH = AgL + (size_t)128 * K;
  const f16* BgL = Bw + (size_t)(m0 + srow) * K + soct * 8;
  const f16* BgH = BgL + (size_t)128 * K;

  const unsigned shbase = (unsigned)(uintptr_t)(&SH[0]);
  const int awr = (int)shbase + tid * 16;           // A write slot (byte)
  const int bwr = (int)shbase + 65536 + tid * 16;   // B write slot (byte)

  // fragment read byte addresses (fswz indep. of mm/nn: +16 rows = +1024 B)
  const int fswz  = oct4 ^ ((l15 >> 1) & 3);
  const int aaddr = (int)shbase + ((wr * 128 + l15) * 4 + fswz) * 16;
  const int baddr = (int)shbase + 65536 + ((wc * 64 + l15) * 4 + fswz) * 16;

  f32x4 acc[8][4];
#pragma unroll
  for (int mm = 0; mm < 8; ++mm)
#pragma unroll
    for (int nn = 0; nn < 4; ++nn)
#pragma unroll
      for (int e = 0; e < 4; ++e) acc[mm][nn][e] = 0.f;

  f16x8 ga0, ga1, gb0, gb1;  // one in-flight staging set (16 VGPR)

  // issue loads for K-step kt (4x dwordx4; vmcnt += 4)
#define STAGE_LOAD(kt)                                                \
  do {                                                                \
    const f16* pa_ = AgL + (kt) * 32;                                 \
    const f16* pA2 = AgH + (kt) * 32;                                 \
    const f16* pb_ = BgL + (kt) * 32;                                 \
    const f16* pB2 = BgH + (kt) * 32;                                 \
    GLOAD(ga0, pa_); GLOAD(ga1, pA2);                                 \
    GLOAD(gb0, pb_); GLOAD(gb1, pB2);                                 \
  } while (0)

  // write staged set into LDS region (kt)&3 (lgkm += 4)
#define STAGE_WRITE(kt)                                               \
  do {                                                                \
    const int wo_ = ((kt) & 3) * 16384;                               \
    DSW(awr + wo_, ga0, 0); DSW(awr + wo_, ga1, 8192);                \
    DSW(bwr + wo_, gb0, 0); DSW(bwr + wo_, gb1, 8192);                \
  } while (0)

  // prologue: region0 staged+written; loads for kt=1 in flight; frags(0)
  STAGE_LOAD(0);
  WAIT_VM0;
  STAGE_WRITE(0);
  WAIT_LGKM(0);          // writes drained (WAR-safe for G reuse)
  STAGE_LOAD(1);
  SBAR;                  // region0 visible to all waves
  __builtin_amdgcn_sched_barrier(0);

  f16x8 af[8], bf[4];
  DSREAD(bf[0], baddr, 0);    DSREAD(bf[1], baddr, 1024);
  DSREAD(bf[2], baddr, 2048); DSREAD(bf[3], baddr, 3072);
  DSREAD(af[0], aaddr, 0);    DSREAD(af[1], aaddr, 1024);
  DSREAD(af[2], aaddr, 2048); DSREAD(af[3], aaddr, 3072);
  DSREAD(af[4], aaddr, 4096); DSREAD(af[5], aaddr, 5120);
  DSREAD(af[6], aaddr, 6144); DSREAD(af[7], aaddr, 7168);

#pragma unroll
  for (int kt = 0; kt < 32; ++kt) {
    // MFMA(kt): frags issued a barrier ago; lgkm queue = 12 reads
    __builtin_amdgcn_s_setprio(1);
    WAIT_LGKM(7);  // bf0-3 + af0
#pragma unroll
    for (int nn = 0; nn < 4; ++nn)
      acc[0][nn] = __builtin_amdgcn_mfma_f32_16x16x32_f16(
          af[0], bf[nn], acc[0][nn], 0, 0, 0);
    WAIT_LGKM(4);  // af1-3
#pragma unroll
    for (int mm = 1; mm < 4; ++mm)
#pragma unroll
      for (int nn = 0; nn < 4; ++nn)
        acc[mm][nn] = __builtin_amdgcn_mfma_f32_16x16x32_f16(
            af[mm], bf[nn], acc[mm][nn], 0, 0, 0);
    WAIT_LGKM(0);  // af4-7
#pragma unroll
    for (int mm = 4; mm < 8; ++mm)
#pragma unroll
      for (int nn = 0; nn < 4; ++nn)
        acc[mm][nn] = __builtin_amdgcn_mfma_f32_16x16x32_f16(
            af[mm], bf[nn], acc[mm][nn], 0, 0, 0);
    __builtin_amdgcn_s_setprio(0);
    __builtin_amdgcn_sched_barrier(0);

    if (kt <= 30) {
      WAIT_VM0;                 // loads(kt+1) arrived (issued 1 phase ago)
      STAGE_WRITE(kt + 1);      // region (kt+1)&3
      WAIT_LGKM(0);             // writes drained: WAR-safe + visibility
      if (kt <= 29) STAGE_LOAD(kt + 2);
      SBAR;
      __builtin_amdgcn_sched_barrier(0);
      // fragment reads for kt+1 (head start across the phase boundary)
      const int ro = ((kt + 1) & 3) * 16384;
      const int aP = aaddr + ro;
      const int bP = baddr + ro;
      DSREAD(bf[0], bP, 0);    DSREAD(bf[1], bP, 1024);
      DSREAD(bf[2], bP, 2048); DSREAD(bf[3], bP, 3072);
      DSREAD(af[0], aP, 0);    DSREAD(af[1], aP, 1024);
      DSREAD(af[2], aP, 2048); DSREAD(af[3], aP, 3072);
      DSREAD(af[4], aP, 4096); DSREAD(af[5], aP, 5120);
      DSREAD(af[6], aP, 6144); DSREAD(af[7], aP, 7168);
    }
  }
#undef STAGE_LOAD
#undef STAGE_WRITE

  // ---------------- epilogues ----------------
  // C/D (16x16): channel col = l15, token row = oct4*4 + r
  if (EPI == 1) {
    float* out = (float*)o0v;
#pragma unroll
    for (int mm = 0; mm < 8; ++mm)
#pragma unroll
      for (int nn = 0; nn < 4; ++nn) {
        const int m = m0 + wc * 64 + nn * 16 + l15;
#pragma unroll
        for (int r = 0; r < 4; ++r) {
          const int n = n0 + wr * 128 + mm * 16 + oct4 * 4 + r;
          out[(size_t)n * 1024 + m] = acc[mm][nn][r];
        }
      }
    return;
  }

  if (m0 < 1024) {
    // forget gate a: sigmoid, stage 128x256 f16 chunks (stride 264)
    float bias[4];
#pragma unroll
    for (int nn = 0; nn < 4; ++nn)
      bias[nn] = gate_b[m0 + wc * 64 + nn * 16 + l15];
    f16* o0 = (f16*)o0v;
#pragma unroll
    for (int ck = 0; ck < 2; ++ck) {
      __builtin_amdgcn_s_barrier();
      asm volatile("" ::: "memory");
      if (wr == ck) {
#pragma unroll
        for (int mm = 0; mm < 8; ++mm)
#pragma unroll
          for (int nn = 0; nn < 4; ++nn) {
            const int ch = wc * 64 + nn * 16 + l15;
#pragma unroll
            for (int r = 0; r < 4; ++r) {
              const int nl = mm * 16 + oct4 * 4 + r;
              SH[nl * 264 + ch] = (f16)sigmoidf_(acc[mm][nn][r] + bias[nn]);
            }
          }
      }
      __builtin_amdgcn_s_barrier();
      asm volatile("" ::: "memory");
#pragma unroll
      for (int j = 0; j < 8; ++j) {
        int s = j * 512 + tid;
        int row = s >> 5, sl = s & 31;
        f16x8 vv = *(const f16x8*)&SH[row * 264 + sl * 8];
        *(f16x8*)(o0 + (size_t)(n0 + ck * 128 + row) * 1024 + m0 + sl * 8) =
            vv;
      }
    }
  } else {
    // bv = sigmoid(bg + bias) * v : even col bg, odd col v (same channel)
    const int c0 = (m0 - 1024) >> 1;
    float biasv[4];
#pragma unroll
    for (int nn = 0; nn < 4; ++nn) {
      const int ml = wc * 64 + nn * 16 + l15;
      biasv[nn] = gate_b[1024 + c0 + (ml >> 1)];
    }
    f16* o1 = (f16*)o1v;
#pragma unroll
    for (int ck = 0; ck < 2; ++ck) {
      __builtin_amdgcn_s_barrier();
      asm volatile("" ::: "memory");
      if (wr == ck) {
#pragma unroll
        for (int mm = 0; mm < 8; ++mm)
#pragma unroll
          for (int nn = 0; nn < 4; ++nn) {
            const int ml = wc * 64 + nn * 16 + l15;
#pragma unroll
            for (int r = 0; r < 4; ++r) {
              float val = acc[mm][nn][r];
              float pv = __shfl_xor(val, 1, 64);  // partner's value
              if (!(lane & 1)) {
                const int nl = mm * 16 + oct4 * 4 + r;
                SH[nl * 136 + (ml >> 1)] =
                    (f16)(sigmoidf_(val + biasv[nn]) * pv);
              }
            }
          }
      }
      __builtin_amdgcn_s_barrier();
      asm volatile("" ::: "memory");
#pragma unroll
      for (int j = 0; j < 4; ++j) {
        int s = j * 512 + tid;
        int row = s >> 4, sl = s & 15;
        f16x8 vv = *(const f16x8*)&SH[row * 136 + sl * 8];
        *(f16x8*)(o1 + (size_t)(n0 + ck * 128 + row) * 1024 + c0 + sl * 8) =
            vv;
      }
    }
  }
}

// ---------------- chunked scan: h_t = a_t*h_{t-1} + bv_t ----------------
// T=4096 = 128 chunks x 32; 2 channels/thread (f16x2).
__global__ __launch_bounds__(256) void scan_pass1(
    const f16x2* __restrict__ a, const f16x2* __restrict__ bv,
    float2* __restrict__ Ac, float2* __restrict__ Uc) {
  const int c2 = blockIdx.x * 256 + threadIdx.x;  // 0..511
  const int j = blockIdx.y;                       // 0..127
  const int b = blockIdx.z;
  const size_t base = ((size_t)(b * 4096 + j * 32)) * 512 + c2;
  float P0 = 1.f, P1 = 1.f, U0 = 0.f, U1 = 0.f;
#pragma unroll 8
  for (int t = 0; t < 32; ++t) {
    const size_t o = base + (size_t)t * 512;
    f16x2 at = a[o], bt = bv[o];
    float a0 = (float)at[0], a1 = (float)at[1];
    P0 *= a0; P1 *= a1;
    U0 = a0 * U0 + (float)bt[0];
    U1 = a1 * U1 + (float)bt[1];
  }
  const size_t o = ((size_t)(b * 128 + j)) * 512 + c2;
  Ac[o] = make_float2(P0, P1);
  Uc[o] = make_float2(U0, U1);
}

// segment-parallel inter-chunk scan: 64 channels x 4 segments of 32 chunks
__global__ __launch_bounds__(256) void scan_pass2(
    const float* __restrict__ Ac, const float* __restrict__ Uc,
    const float* __restrict__ h_prev, float* __restrict__ Hs,
    float* __restrict__ hlast) {
  __shared__ float SA[4][64], SU[4][64];
  const int tid = threadIdx.x;
  const int seg = tid >> 6;            // 0..3
  const int cl  = tid & 63;
  const int ch  = blockIdx.x * 64 + cl;  // 0..4095
  const int b = ch >> 10, c = ch & 1023;
  float A = 1.f, U = 0.f;
  for (int t = 0; t < 32; ++t) {
    const int j = seg * 32 + t;
    const size_t o = ((size_t)(b * 128 + j)) * 1024 + c;
    float av = Ac[o], uv = Uc[o];
    U = av * U + uv;
    A = av * A;
  }
  SA[seg][cl] = A;
  SU[seg][cl] = U;
  __syncthreads();
  float Ae = 1.f, Ue = 0.f;
  for (int s = 0; s < seg; ++s) {
    float av = SA[s][cl], uv = SU[s][cl];
    Ue = av * Ue + uv;
    Ae = av * Ae;
  }
  float H = Ae * h_prev[b * 1024 + c] + Ue;  // state entering my segment
  for (int t = 0; t < 32; ++t) {
    const int j = seg * 32 + t;
    const size_t o = ((size_t)(b * 128 + j)) * 1024 + c;
    Hs[o] = H;
    H = Ac[o] * H + Uc[o];
  }
  if (seg == 3) hlast[b * 1024 + c] = H;
}

__global__ __launch_bounds__(256) void scan_pass3(
    const f16x2* __restrict__ a, const f16x2* __restrict__ bv,
    const float2* __restrict__ Hs, f16x2* __restrict__ hb) {
  const int c2 = blockIdx.x * 256 + threadIdx.x;
  const int j = blockIdx.y;
  const int b = blockIdx.z;
  const size_t base = ((size_t)(b * 4096 + j * 32)) * 512 + c2;
  float2 H = Hs[((size_t)(b * 128 + j)) * 512 + c2];
  float h0 = H.x, h1 = H.y;
#pragma unroll 8
  for (int t = 0; t < 32; ++t) {
    const size_t o = base + (size_t)t * 512;
    f16x2 at = a[o], bt = bv[o];
    h0 = (float)at[0] * h0 + (float)bt[0];
    h1 = (float)at[1] * h1 + (float)bt[1];
    f16x2 hv; hv[0] = (f16)h0; hv[1] = (f16)h1;
    hb[o] = hv;
  }
}

extern "C" void kernel_launch(void* const* d_in, const int* in_sizes, int n_in,
                              void* d_out, int out_size, void* d_ws,
                              size_t ws_size, hipStream_t stream) {
  const float* x       = (const float*)d_in[0];
  const float* h_prev  = (const float*)d_in[1];
  const float* gate_w  = (const float*)d_in[2];
  const float* gate_b  = (const float*)d_in[3];
  const float* value_w = (const float*)d_in[4];
  const float* out_w   = (const float*)d_in[5];
  float* out = (float*)d_out;

  char* ws = (char*)d_ws;
  // ws layout (bytes), total ~115.3 MB:
  f16*   xh   = (f16*)(ws);                    // 33,554,432  x f16; reused as h
  f16*   wgv  = (f16*)(ws + 33554432);         //  6,291,456  packed weights
  f16*   owb  = (f16*)(ws + 39845888);         //  2,097,152  out_w f16
  f16*   abuf = (f16*)(ws + 41943040);         // 33,554,432  forget gate a
  f16*   bvb  = (f16*)(ws + 75497472);         // 33,554,432  bv = bg*v
  float* Ac   = (float*)(ws + 109051904);      //  2,097,152
  float* Uc   = (float*)(ws + 111149056);      //  2,097,152
  float* Hs   = (float*)(ws + 113246208);      //  2,097,152
  float* hlast = out + 16777216;

  // fused cast + weight packing
  cast_pack<<<10240, 256, 0, stream>>>(x, gate_w, value_w, out_w, xh, wgv,
                                       owb);

  // gates+values GEMM, fused sigmoid + bv epilogue (M=3072 -> 12 m-tiles)
  gemm256<0><<<dim3(768), 512, 0, stream>>>(xh, wgv, gate_b, abuf, bvb, 12);

  // chunked scan (128 chunks x 32)
  scan_pass1<<<dim3(2, 128, 4), 256, 0, stream>>>(
      (const f16x2*)abuf, (const f16x2*)bvb, (float2*)Ac, (float2*)Uc);
  scan_pass2<<<64, 256, 0, stream>>>(Ac, Uc, h_prev, Hs, hlast);
  scan_pass3<<<dim3(2, 128, 4), 256, 0, stream>>>(
      (const f16x2*)abuf, (const f16x2*)bvb, (const float2*)Hs, (f16x2*)xh);

  // output GEMM -> y fp32 (M=1024 -> 4 m-tiles)
  gemm256<1><<<dim3(256), 512, 0, stream>>>(xh, owb, nullptr, out, nullptr, 4);
}

// Round 10
// 364.241 us; speedup vs baseline: 1.4532x; 1.0048x over previous
//
#include <hip/hip_runtime.h>
#include <cstdint>
#include <cstddef>

// GLA layer: B=4, T=4096, D=1024, H=16, S=64
// fp16 pipeline, packed weights (a rows | interleaved bg/v rows).
// GEMMs = 256x256 tile, 8 waves, 16x16x32 MFMA, 32 K-phases (R5 schedule:
// rotated frag ds_reads, 3-phase gload_lds lead, counted lgkm(7/4/0),
// counted vmcnt, one opaque barrier per phase).
// ROUND 10 = ROUND 8 RESUBMIT (two infra failures, no data yet):
// L2-LOCALITY BLOCK REMAP. Old swizzle gave each XCD ~3 n-panels x ALL
// m-panels -> B working set 6 MB > 4 MB L2 -> staging reads chronically
// L2-miss (FETCH 156 MB vs 38 ideal); the resulting memory-service wall
// (~2500 cyc/phase) was invariant to every schedule/mechanism change
// (R0-R7). New map: M split in 2 halves (B-half 3 MB L2-fits); each XCD
// (bid%8) owns a disjoint 8-wide n-range, m varies fastest -> concurrent
// blocks share B (resident) and cluster same-n A reads in time.
// GEMM1 epilogue: a = sigmoid(.), bv = sigmoid(.)*v (lane-pair shfl),
// LDS-staged f16x8 coalesced stores. Scan: 128 chunks x 32 steps,
// segment-parallel pass2. GEMM2 -> y fp32 direct stores.

typedef _Float16 f16;
typedef _Float16 f16x2 __attribute__((ext_vector_type(2)));
typedef _Float16 f16x8 __attribute__((ext_vector_type(8)));
typedef float    f32x4 __attribute__((ext_vector_type(4)));

__device__ __forceinline__ void gload_lds16(const void* g, void* l) {
  __builtin_amdgcn_global_load_lds(
      (const __attribute__((address_space(1))) void*)g,
      (__attribute__((address_space(3))) void*)l, 16, 0, 0);
}

__device__ __forceinline__ float sigmoidf_(float x) {
  return 1.0f / (1.0f + __expf(-x));
}

// ---------------- fused cast+pack fp32 -> fp16 ----------------
__global__ __launch_bounds__(256) void cast_pack(
    const float* __restrict__ x, const float* __restrict__ gw,
    const float* __restrict__ vw, const float* __restrict__ ow,
    f16* __restrict__ xh, f16* __restrict__ wgv, f16* __restrict__ owb) {
  const int XG = 2097152, GG = 262144, VG = 131072, OG = 131072;
  int id = blockIdx.x * 256 + threadIdx.x;
  const float* src;
  f16* dst;
  if (id < XG) {
    src = x + (size_t)id * 8;
    dst = xh + (size_t)id * 8;
  } else if (id < XG + GG) {
    int g = id - XG;
    int row = g >> 7, col = g & 127;
    int drow = (row < 1024) ? row : (1024 + 2 * (row - 1024));
    src = gw + ((size_t)row << 10) + col * 8;
    dst = wgv + ((size_t)drow << 10) + col * 8;
  } else if (id < XG + GG + VG) {
    int g = id - XG - GG;
    int row = g >> 7, col = g & 127;
    int drow = 1024 + 2 * row + 1;
    src = vw + ((size_t)row << 10) + col * 8;
    dst = wgv + ((size_t)drow << 10) + col * 8;
  } else if (id < XG + GG + VG + OG) {
    int g = id - XG - GG - VG;
    src = ow + (size_t)g * 8;
    dst = owb + (size_t)g * 8;
  } else {
    return;
  }
  float4 v0 = ((const float4*)src)[0], v1 = ((const float4*)src)[1];
  f16x8 o;
  o[0] = (f16)v0.x; o[1] = (f16)v0.y; o[2] = (f16)v0.z; o[3] = (f16)v0.w;
  o[4] = (f16)v1.x; o[5] = (f16)v1.y; o[6] = (f16)v1.z; o[7] = (f16)v1.w;
  *(f16x8*)dst = o;
}

// opaque LDS read: invisible to the compiler's waitcnt alias tracking.
#define DSREAD(dst, addr, off)                                        \
  asm volatile("ds_read_b128 %0, %1 offset:%2"                       \
               : "=v"(dst)                                            \
               : "v"(addr), "i"(off))

#define WAIT_LGKM(n)                                                  \
  asm volatile("s_waitcnt lgkmcnt(" #n ")" ::: "memory");             \
  __builtin_amdgcn_sched_barrier(0)

// opaque barrier (no compiler-attached waits)
#define SBAR asm volatile("s_barrier" ::: "memory")

// ---- 256x256 fp16 MFMA GEMM: C[N,M] = A[N,K] * B[M,K]^T ----
// 8 waves (2 token-halves x 4 channel-quarters), per-wave 128x64 output.
template <int EPI>
__global__ __launch_bounds__(512, 2) void gemm256(
    const f16* __restrict__ A, const f16* __restrict__ Bw,
    const float* __restrict__ gate_b, void* __restrict__ o0v,
    void* __restrict__ o1v, int Mtiles) {
  constexpr int K = 1024;
  __shared__ __align__(16) f16 SH[65536];  // 128 KiB
  f16* LA = SH;          // 4 regions x 8192 f16 (16 KB each)
  f16* LB = SH + 32768;

  const int tid  = threadIdx.x;
  const int lane = tid & 63;
  const int l15  = lane & 15;
  const int oct4 = lane >> 4;   // k-octet within a 32-wide kstep
  const int wid  = tid >> 6;
  const int wr   = wid >> 2;    // 0..1 token half
  const int wc   = wid & 3;     // 0..3 channel quarter

  // L2-locality remap: XCD = bid%8 owns a disjoint 8-wide n-range;
  // m varies FASTEST within an XCD's sequence; M split into 2 halves
  // (EPI==0) so the active B half (6 panels = 3 MB) is L2-resident.
  const int bid = blockIdx.x;
  const int x8  = bid & 7;
  const int sq  = bid >> 3;     // 0..95 (EPI0) / 0..31 (EPI1)
  int mi, ni;
  if (EPI == 0) {               // Mtiles=12: 2 halves x (6m x 8n) per XCD
    const int half = sq / 48;
    const int j    = sq % 48;
    mi = (j % 6) + 6 * half;
    ni = x8 * 8 + j / 6;
  } else {                      // Mtiles=4: 4m x 8n per XCD
    mi = sq & 3;
    ni = x8 * 8 + (sq >> 2);
  }
  const int m0 = mi * 256;
  const int n0 = ni * 256;

  // staging: thread covers (row=tid>>2, physOct=(tid&3)^((row>>1)&3))
  const int srow = tid >> 2;
  const int soct = (tid & 3) ^ ((srow >> 1) & 3);
  const f16* Ag = A  + (size_t)(n0 + srow) * K + soct * 8;
  const f16* Bg = Bw + (size_t)(m0 + srow) * K + soct * 8;
  f16* Al = LA + tid * 8;
  f16* Bl = LB + tid * 8;

  // fragment read byte addresses (fswz indep. of mm/nn: +16 rows = +1024 B)
  const int fswz  = oct4 ^ ((l15 >> 1) & 3);
  const unsigned shbase = (unsigned)(uintptr_t)(&SH[0]);
  const int aaddr = (int)shbase + ((wr * 128 + l15) * 4 + fswz) * 16;
  const int baddr = (int)shbase + 65536 + ((wc * 64 + l15) * 4 + fswz) * 16;

  f32x4 acc[8][4];
#pragma unroll
  for (int mm = 0; mm < 8; ++mm)
#pragma unroll
    for (int nn = 0; nn < 4; ++nn)
#pragma unroll
      for (int e = 0; e < 4; ++e) acc[mm][nn][e] = 0.f;

  // stage K-step kt's A+B half-panels into LDS region kt&3 (4 gloads/thread)
#define STAGE_AB(kt)                                                  \
  do {                                                                \
    const f16* sa_ = Ag + (kt) * 32;                                  \
    const f16* sb_ = Bg + (kt) * 32;                                  \
    f16* da_ = Al + ((kt) & 3) * 8192;                                \
    f16* db_ = Bl + ((kt) & 3) * 8192;                                \
    gload_lds16(sa_, da_);                                            \
    gload_lds16(sa_ + 128 * K, da_ + 4096);                           \
    gload_lds16(sb_, db_);                                            \
    gload_lds16(sb_ + 128 * K, db_ + 4096);                           \
  } while (0)

  // prologue: regions 0,1,2 (12 gloads); wait region 0; read frags(0)
  STAGE_AB(0);
  STAGE_AB(1);
  STAGE_AB(2);
  asm volatile("s_waitcnt vmcnt(8)" ::: "memory");
  SBAR;
  __builtin_amdgcn_sched_barrier(0);

  f16x8 af[8], bf[4];
  DSREAD(bf[0], baddr, 0);    DSREAD(bf[1], baddr, 1024);
  DSREAD(bf[2], baddr, 2048); DSREAD(bf[3], baddr, 3072);
  DSREAD(af[0], aaddr, 0);    DSREAD(af[1], aaddr, 1024);
  DSREAD(af[2], aaddr, 2048); DSREAD(af[3], aaddr, 3072);
  DSREAD(af[4], aaddr, 4096); DSREAD(af[5], aaddr, 5120);
  DSREAD(af[6], aaddr, 6144); DSREAD(af[7], aaddr, 7168);

#pragma unroll
  for (int kt = 0; kt < 32; ++kt) {
    // deep prefetch: issue region kt+3 (lead ~2.3 phases)
    if (kt <= 28) STAGE_AB(kt + 3);

    // MFMA(kt): frags issued a barrier ago; counted lgkm waits rarely stall
    __builtin_amdgcn_s_setprio(1);
    WAIT_LGKM(7);  // bf0-3 + af0 ready
#pragma unroll
    for (int nn = 0; nn < 4; ++nn)
      acc[0][nn] = __builtin_amdgcn_mfma_f32_16x16x32_f16(
          af[0], bf[nn], acc[0][nn], 0, 0, 0);
    WAIT_LGKM(4);  // af1-3 ready
#pragma unroll
    for (int mm = 1; mm < 4; ++mm)
#pragma unroll
      for (int nn = 0; nn < 4; ++nn)
        acc[mm][nn] = __builtin_amdgcn_mfma_f32_16x16x32_f16(
            af[mm], bf[nn], acc[mm][nn], 0, 0, 0);
    WAIT_LGKM(0);  // af4-7 ready
#pragma unroll
    for (int mm = 4; mm < 8; ++mm)
#pragma unroll
      for (int nn = 0; nn < 4; ++nn)
        acc[mm][nn] = __builtin_amdgcn_mfma_f32_16x16x32_f16(
            af[mm], bf[nn], acc[mm][nn], 0, 0, 0);
    __builtin_amdgcn_s_setprio(0);
    __builtin_amdgcn_sched_barrier(0);

    if (kt < 31) {
      // guarantee region kt+1 landed (per-wave), then sync all waves,
      // then issue next phase's fragment reads (head start over barrier)
      if (kt <= 28) {
        asm volatile("s_waitcnt vmcnt(8)" ::: "memory");
      } else if (kt == 29) {
        asm volatile("s_waitcnt vmcnt(4)" ::: "memory");
      } else {
        asm volatile("s_waitcnt vmcnt(0)" ::: "memory");
      }
      SBAR;
      __builtin_amdgcn_sched_barrier(0);
      const int ro = ((kt + 1) & 3) * 16384;
      const int aP = aaddr + ro;
      const int bP = baddr + ro;
      DSREAD(bf[0], bP, 0);    DSREAD(bf[1], bP, 1024);
      DSREAD(bf[2], bP, 2048); DSREAD(bf[3], bP, 3072);
      DSREAD(af[0], aP, 0);    DSREAD(af[1], aP, 1024);
      DSREAD(af[2], aP, 2048); DSREAD(af[3], aP, 3072);
      DSREAD(af[4], aP, 4096); DSREAD(af[5], aP, 5120);
      DSREAD(af[6], aP, 6144); DSREAD(af[7], aP, 7168);
    }
  }
#undef STAGE_AB

  // ---------------- epilogues ----------------
  // C/D (16x16): channel col = l15, token row = oct4*4 + r
  if (EPI == 1) {
    float* out = (float*)o0v;
#pragma unroll
    for (int mm = 0; mm < 8; ++mm)
#pragma unroll
      for (int nn = 0; nn < 4; ++nn) {
        const int m = m0 + wc * 64 + nn * 16 + l15;
#pragma unroll
        for (int r = 0; r < 4; ++r) {
          const int n = n0 + wr * 128 + mm * 16 + oct4 * 4 + r;
          out[(size_t)n * 1024 + m] = acc[mm][nn][r];
        }
      }
    return;
  }

  if (m0 < 1024) {
    // forget gate a: sigmoid, stage 128x256 f16 chunks (stride 264)
    float bias[4];
#pragma unroll
    for (int nn = 0; nn < 4; ++nn)
      bias[nn] = gate_b[m0 + wc * 64 + nn * 16 + l15];
    f16* o0 = (f16*)o0v;
#pragma unroll
    for (int ck = 0; ck < 2; ++ck) {
      __builtin_amdgcn_s_barrier();
      asm volatile("" ::: "memory");
      if (wr == ck) {
#pragma unroll
        for (int mm = 0; mm < 8; ++mm)
#pragma unroll
          for (int nn = 0; nn < 4; ++nn) {
            const int ch = wc * 64 + nn * 16 + l15;
#pragma unroll
            for (int r = 0; r < 4; ++r) {
              const int nl = mm * 16 + oct4 * 4 + r;
              SH[nl * 264 + ch] = (f16)sigmoidf_(acc[mm][nn][r] + bias[nn]);
            }
          }
      }
      __builtin_amdgcn_s_barrier();
      asm volatile("" ::: "memory");
#pragma unroll
      for (int j = 0; j < 8; ++j) {
        int s = j * 512 + tid;
        int row = s >> 5, sl = s & 31;
        f16x8 vv = *(const f16x8*)&SH[row * 264 + sl * 8];
        *(f16x8*)(o0 + (size_t)(n0 + ck * 128 + row) * 1024 + m0 + sl * 8) =
            vv;
      }
    }
  } else {
    // bv = sigmoid(bg + bias) * v : even col bg, odd col v (same channel)
    const int c0 = (m0 - 1024) >> 1;
    float biasv[4];
#pragma unroll
    for (int nn = 0; nn < 4; ++nn) {
      const int ml = wc * 64 + nn * 16 + l15;
      biasv[nn] = gate_b[1024 + c0 + (ml >> 1)];
    }
    f16* o1 = (f16*)o1v;
#pragma unroll
    for (int ck = 0; ck < 2; ++ck) {
      __builtin_amdgcn_s_barrier();
      asm volatile("" ::: "memory");
      if (wr == ck) {
#pragma unroll
        for (int mm = 0; mm < 8; ++mm)
#pragma unroll
          for (int nn = 0; nn < 4; ++nn) {
            const int ml = wc * 64 + nn * 16 + l15;
#pragma unroll
            for (int r = 0; r < 4; ++r) {
              float val = acc[mm][nn][r];
              float pv = __shfl_xor(val, 1, 64);  // partner's value
              if (!(lane & 1)) {
                const int nl = mm * 16 + oct4 * 4 + r;
                SH[nl * 136 + (ml >> 1)] =
                    (f16)(sigmoidf_(val + biasv[nn]) * pv);
              }
            }
          }
      }
      __builtin_amdgcn_s_barrier();
      asm volatile("" ::: "memory");
#pragma unroll
      for (int j = 0; j < 4; ++j) {
        int s = j * 512 + tid;
        int row = s >> 4, sl = s & 15;
        f16x8 vv = *(const f16x8*)&SH[row * 136 + sl * 8];
        *(f16x8*)(o1 + (size_t)(n0 + ck * 128 + row) * 1024 + c0 + sl * 8) =
            vv;
      }
    }
  }
}

// ---------------- chunked scan: h_t = a_t*h_{t-1} + bv_t ----------------
// T=4096 = 128 chunks x 32; 2 channels/thread (f16x2).
__global__ __launch_bounds__(256) void scan_pass1(
    const f16x2* __restrict__ a, const f16x2* __restrict__ bv,
    float2* __restrict__ Ac, float2* __restrict__ Uc) {
  const int c2 = blockIdx.x * 256 + threadIdx.x;  // 0..511
  const int j = blockIdx.y;                       // 0..127
  const int b = blockIdx.z;
  const size_t base = ((size_t)(b * 4096 + j * 32)) * 512 + c2;
  float P0 = 1.f, P1 = 1.f, U0 = 0.f, U1 = 0.f;
#pragma unroll 8
  for (int t = 0; t < 32; ++t) {
    const size_t o = base + (size_t)t * 512;
    f16x2 at = a[o], bt = bv[o];
    float a0 = (float)at[0], a1 = (float)at[1];
    P0 *= a0; P1 *= a1;
    U0 = a0 * U0 + (float)bt[0];
    U1 = a1 * U1 + (float)bt[1];
  }
  const size_t o = ((size_t)(b * 128 + j)) * 512 + c2;
  Ac[o] = make_float2(P0, P1);
  Uc[o] = make_float2(U0, U1);
}

// segment-parallel inter-chunk scan: 64 channels x 4 segments of 32 chunks
__global__ __launch_bounds__(256) void scan_pass2(
    const float* __restrict__ Ac, const float* __restrict__ Uc,
    const float* __restrict__ h_prev, float* __restrict__ Hs,
    float* __restrict__ hlast) {
  __shared__ float SA[4][64], SU[4][64];
  const int tid = threadIdx.x;
  const int seg = tid >> 6;            // 0..3
  const int cl  = tid & 63;
  const int ch  = blockIdx.x * 64 + cl;  // 0..4095
  const int b = ch >> 10, c = ch & 1023;
  float A = 1.f, U = 0.f;
  for (int t = 0; t < 32; ++t) {
    const int j = seg * 32 + t;
    const size_t o = ((size_t)(b * 128 + j)) * 1024 + c;
    float av = Ac[o], uv = Uc[o];
    U = av * U + uv;
    A = av * A;
  }
  SA[seg][cl] = A;
  SU[seg][cl] = U;
  __syncthreads();
  float Ae = 1.f, Ue = 0.f;
  for (int s = 0; s < seg; ++s) {
    float av = SA[s][cl], uv = SU[s][cl];
    Ue = av * Ue + uv;
    Ae = av * Ae;
  }
  float H = Ae * h_prev[b * 1024 + c] + Ue;  // state entering my segment
  for (int t = 0; t < 32; ++t) {
    const int j = seg * 32 + t;
    const size_t o = ((size_t)(b * 128 + j)) * 1024 + c;
    Hs[o] = H;
    H = Ac[o] * H + Uc[o];
  }
  if (seg == 3) hlast[b * 1024 + c] = H;
}

__global__ __launch_bounds__(256) void scan_pass3(
    const f16x2* __restrict__ a, const f16x2* __restrict__ bv,
    const float2* __restrict__ Hs, f16x2* __restrict__ hb) {
  const int c2 = blockIdx.x * 256 + threadIdx.x;
  const int j = blockIdx.y;
  const int b = blockIdx.z;
  const size_t base = ((size_t)(b * 4096 + j * 32)) * 512 + c2;
  float2 H = Hs[((size_t)(b * 128 + j)) * 512 + c2];
  float h0 = H.x, h1 = H.y;
#pragma unroll 8
  for (int t = 0; t < 32; ++t) {
    const size_t o = base + (size_t)t * 512;
    f16x2 at = a[o], bt = bv[o];
    h0 = (float)at[0] * h0 + (float)bt[0];
    h1 = (float)at[1] * h1 + (float)bt[1];
    f16x2 hv; hv[0] = (f16)h0; hv[1] = (f16)h1;
    hb[o] = hv;
  }
}

extern "C" void kernel_launch(void* const* d_in, const int* in_sizes, int n_in,
                              void* d_out, int out_size, void* d_ws,
                              size_t ws_size, hipStream_t stream) {
  const float* x       = (const float*)d_in[0];
  const float* h_prev  = (const float*)d_in[1];
  const float* gate_w  = (const float*)d_in[2];
  const float* gate_b  = (const float*)d_in[3];
  const float* value_w = (const float*)d_in[4];
  const float* out_w   = (const float*)d_in[5];
  float* out = (float*)d_out;

  char* ws = (char*)d_ws;
  // ws layout (bytes), total ~115.3 MB:
  f16*   xh   = (f16*)(ws);                    // 33,554,432  x f16; reused as h
  f16*   wgv  = (f16*)(ws + 33554432);         //  6,291,456  packed weights
  f16*   owb  = (f16*)(ws + 39845888);         //  2,097,152  out_w f16
  f16*   abuf = (f16*)(ws + 41943040);         // 33,554,432  forget gate a
  f16*   bvb  = (f16*)(ws + 75497472);         // 33,554,432  bv = bg*v
  float* Ac   = (float*)(ws + 109051904);      //  2,097,152
  float* Uc   = (float*)(ws + 111149056);      //  2,097,152
  float* Hs   = (float*)(ws + 113246208);      //  2,097,152
  float* hlast = out + 16777216;

  // fused cast + weight packing
  cast_pack<<<10240, 256, 0, stream>>>(x, gate_w, value_w, out_w, xh, wgv,
                                       owb);

  // gates+values GEMM, fused sigmoid + bv epilogue (M=3072 -> 12 m-tiles)
  gemm256<0><<<dim3(768), 512, 0, stream>>>(xh, wgv, gate_b, abuf, bvb, 12);

  // chunked scan (128 chunks x 32)
  scan_pass1<<<dim3(2, 128, 4), 256, 0, stream>>>(
      (const f16x2*)abuf, (const f16x2*)bvb, (float2*)Ac, (float2*)Uc);
  scan_pass2<<<64, 256, 0, stream>>>(Ac, Uc, h_prev, Hs, hlast);
  scan_pass3<<<dim3(2, 128, 4), 256, 0, stream>>>(
      (const f16x2*)abuf, (const f16x2*)bvb, (const float2*)Hs, (f16x2*)xh);

  // output GEMM -> y fp32 (M=1024 -> 4 m-tiles)
  gemm256<1><<<dim3(256), 512, 0, stream>>>(xh, owb, nullptr, out, nullptr, 4);
}